// Round 1
// 4019.793 us; speedup vs baseline: 2.0810x; 2.0810x over previous
//
#include <hip/hip_runtime.h>
#include <math.h>
#include <stddef.h>

#define D_MODEL 512
#define NHEAD   8
#define DHEAD   64
#define BATCH   8
#define SEQ     512
#define NLAYER  6
#define DFFN    2048
#define ROWS    (BATCH * SEQ)   // 4096
#define TB      16384L          // bytes per split tile: hi plane 8KB + lo plane 8KB

typedef __attribute__((ext_vector_type(4))) float f32x4;
typedef __attribute__((ext_vector_type(8))) short bf16x8;   // 8 bf16 = 4 VGPRs

// ---------------------------------------------------------------------------
// fp32 -> (hi, lo) bf16 split, RNE.  combined mantissa ~16-17 bits.
// ---------------------------------------------------------------------------
__device__ __forceinline__ unsigned bf16_rne(float f) {
    unsigned u = __float_as_uint(f);
    return (u + 0x7fffu + ((u >> 16) & 1u)) >> 16;
}
__device__ __forceinline__ void split_bf16(float f, unsigned& h, unsigned& l) {
    h = bf16_rne(f);
    float hf = __uint_as_float(h << 16);
    l = bf16_rne(f - hf);
}

// swizzled byte offset inside one 64x64 bf16 plane (row-major, 128B rows).
// XOR of 16B-slot index with (row&7): conflict-free ds_read_b128 / writes.
__device__ __forceinline__ int swz(int row, int kbyte) {
    return row * 128 + (kbyte ^ ((row & 7) << 4));
}

// async global->LDS, 16B per lane; LDS dest is wave-uniform base + lane*16
__device__ __forceinline__ void gll16(const void* g, void* l) {
    __builtin_amdgcn_global_load_lds(
        (const __attribute__((address_space(1))) void*)g,
        (__attribute__((address_space(3))) void*)l, 16, 0, 0);
}

// ---------------------------------------------------------------------------
// Embedding gather + write x fp32 and x split tiles
// ---------------------------------------------------------------------------
__global__ __launch_bounds__(128) void embed_kernel(
    const int* __restrict__ seq, const int* __restrict__ pos,
    const float* __restrict__ emb, const float* __restrict__ pemb,
    float* __restrict__ x, char* __restrict__ xsplit)
{
    int row = blockIdx.x;
    int tok = seq[row];
    int p   = pos[row];
    int i = threadIdx.x;                  // 0..127 -> 4 floats each
    float4 a = ((const float4*)(emb  + (size_t)tok * D_MODEL))[i];
    float4 b = ((const float4*)(pemb + (size_t)p   * D_MODEL))[i];
    float4 v = make_float4(a.x + b.x, a.y + b.y, a.z + b.z, a.w + b.w);
    ((float4*)(x + (size_t)row * D_MODEL))[i] = v;

    unsigned h0,h1,h2,h3,l0,l1,l2,l3;
    split_bf16(v.x,h0,l0); split_bf16(v.y,h1,l1);
    split_bf16(v.z,h2,l2); split_bf16(v.w,h3,l3);
    uint2 hp, lp;
    hp.x = h0 | (h1<<16); hp.y = h2 | (h3<<16);
    lp.x = l0 | (l1<<16); lp.y = l2 | (l3<<16);
    int mt = row >> 6, m = row & 63;
    int k  = i * 4;
    int kt = k >> 6, kl = k & 63;
    char* tp = xsplit + (size_t)(mt * 8 + kt) * TB + swz(m, kl * 2);
    *(uint2*)tp = hp;
    *(uint2*)(tp + 8192) = lp;
}

// ---------------------------------------------------------------------------
// Split a row-major fp32 [4096][512] activation into A-style tiles (enc_output)
// grid: 512 blocks = mt*8+kt
// ---------------------------------------------------------------------------
__global__ __launch_bounds__(256) void asplit_kernel(
    const float* __restrict__ A, char* __restrict__ dst)
{
    int mt = blockIdx.x >> 3, kt = blockIdx.x & 7;
    int t = threadIdx.x;
    int m  = t >> 2;              // 0..63
    int kq = (t & 3) * 4;         // 0,4,8,12
    const float* src = A + (size_t)(mt * 64 + m) * D_MODEL + kt * 64;
    char* dp = dst + (size_t)blockIdx.x * TB;
    #pragma unroll
    for (int rep = 0; rep < 4; ++rep) {
        int k = rep * 16 + kq;
        float4 v = *(const float4*)(src + k);
        unsigned h0,h1,h2,h3,l0,l1,l2,l3;
        split_bf16(v.x,h0,l0); split_bf16(v.y,h1,l1);
        split_bf16(v.z,h2,l2); split_bf16(v.w,h3,l3);
        uint2 hp, lp;
        hp.x = h0 | (h1<<16); hp.y = h2 | (h3<<16);
        lp.x = l0 | (l1<<16); lp.y = l2 | (l3<<16);
        char* pp = dp + swz(m, k * 2);
        *(uint2*)pp = hp;
        *(uint2*)(pp + 8192) = lp;
    }
}

// ---------------------------------------------------------------------------
// Split one layer's 10 weight matrices into B-style tiles (rows = n, k-contig)
// grid: 1024 blocks. Tile order:
//   [0,64) wq [64,128) wk [128,192) wv [192,256) pw
//   [256,320) ewq [320,384) ewk [384,448) ewv [448,512) epw
//   [512,768) w1 (NT=32,KT=8)   [768,1024) w2 (NT=8,KT=32)
// ---------------------------------------------------------------------------
__global__ __launch_bounds__(256) void wsplit_kernel(
    const float* __restrict__ wq, const float* __restrict__ wk,
    const float* __restrict__ wv, const float* __restrict__ pw,
    const float* __restrict__ ewq, const float* __restrict__ ewk,
    const float* __restrict__ ewv, const float* __restrict__ epw,
    const float* __restrict__ w1, const float* __restrict__ w2,
    char* __restrict__ outb)
{
    int bid = blockIdx.x;
    const float* W = nullptr;
    int bhead = 0, ldw = 512, nt, kt;
    if (bid < 512) {
        int m = bid >> 6;
        switch (m) {
            case 0: W = wq;  bhead = 1; break;
            case 1: W = wk;  bhead = 1; break;
            case 2: W = wv;  bhead = 1; break;
            case 3: W = pw;  break;
            case 4: W = ewq; bhead = 1; break;
            case 5: W = ewk; bhead = 1; break;
            case 6: W = ewv; bhead = 1; break;
            default: W = epw; break;
        }
        int tile = bid & 63; nt = tile >> 3; kt = tile & 7;
    } else if (bid < 768) {
        W = w1; ldw = DFFN;
        int tile = bid - 512; nt = tile >> 3; kt = tile & 7;
    } else {
        W = w2; ldw = 512;
        int tile = bid - 768; nt = tile >> 5; kt = tile & 31;
    }
    int t = threadIdx.x;
    int n  = t >> 2;              // tile row (= output col n)
    int kq = (t & 3) * 4;
    int ng = nt * 64 + n;
    char* dp = outb + (size_t)bid * TB;
    #pragma unroll
    for (int rep = 0; rep < 4; ++rep) {
        int k = rep * 16 + kq;
        unsigned h[4], lo[4];
        #pragma unroll
        for (int j = 0; j < 4; ++j) {
            int kg = kt * 64 + k + j;
            size_t a = bhead ? ((size_t)(ng >> 6) * 512 + kg) * 64 + (ng & 63)
                             : (size_t)kg * ldw + ng;
            split_bf16(W[a], h[j], lo[j]);
        }
        uint2 hp, lp;
        hp.x = h[0] | (h[1]<<16); hp.y = h[2] | (h[3]<<16);
        lp.x = lo[0] | (lo[1]<<16); lp.y = lo[2] | (lo[3]<<16);
        char* pp = dp + swz(n, k * 2);
        *(uint2*)pp = hp;
        *(uint2*)(pp + 8192) = lp;
    }
}

// ---------------------------------------------------------------------------
// Split-bf16 (3xMFMA) GEMM.  64x64 tile, BK=64, 256 threads = 4 waves,
// wave-tile 32x32 as 2x2 16x16x32 fragments, double-buffered LDS.
// amode: 0 = A pre-split tiles (global_load_lds)  1 = A fp32, convert in stage
// emode: 0 = C fp32 (+bias)  1 = C split tiles  2 = split+relu  3 = split transposed (B-style)
// ---------------------------------------------------------------------------
__global__ __launch_bounds__(256) void gemm2_kernel(
    const char* __restrict__ Asp, const float* __restrict__ Af,
    const char* __restrict__ Bsp,
    float* __restrict__ Cf, char* __restrict__ Csp,
    const float* __restrict__ bias,
    int KT,
    long a_mt, int lda, long a_s1, long a_s2,
    long b_nt, long b_kt, long b_s1, long b_s2,
    int ldc,
    long c_mt, long c_nt, long c_s1, long c_s2,
    int zdiv, int amode, int emode)
{
    __shared__ __align__(16) char smem[65536];
    int z  = blockIdx.z;
    int z1 = z / zdiv, z2 = z % zdiv;
    int nt = blockIdx.x, mt = blockIdx.y;
    int tid = threadIdx.x;
    int w = tid >> 6, l = tid & 63;
    int l15 = l & 15, lg = l >> 4;
    int wr = w >> 1, wc = w & 1;

    const char*  Abase = (amode == 0) ? (Asp + (size_t)mt * a_mt) : nullptr;
    const float* Afp   = (amode == 1) ? (Af + (size_t)a_s1 * z1 + (size_t)a_s2 * z2
                                            + (size_t)(mt * 64) * lda) : nullptr;
    const char*  Bbase = Bsp + (size_t)nt * b_nt + (size_t)b_s1 * z1 + (size_t)b_s2 * z2;

    f32x4 zv = {0.f, 0.f, 0.f, 0.f};
    f32x4 acc[2][2] = {{zv, zv}, {zv, zv}};

    auto stage = [&](int buf, int kt) {
        char* dst = smem + (buf << 15);
        if (amode == 0) {
            if (w < 2) {
                const char* src = Abase + (size_t)kt * TB + (w << 13) + l * 16;
                char* d = dst + (w << 13);
                #pragma unroll
                for (int i = 0; i < 8; ++i)
                    gll16(src + i * 1024, d + i * 1024);
            }
        } else {
            const float* s = Afp + kt * 64;
            #pragma unroll
            for (int rep = 0; rep < 4; ++rep) {
                int m  = (tid >> 4) + rep * 16;
                int kq = (tid & 15) * 4;
                float4 v = *(const float4*)(s + (size_t)m * lda + kq);
                unsigned h0,h1,h2,h3,l0,l1,l2,l3;
                split_bf16(v.x,h0,l0); split_bf16(v.y,h1,l1);
                split_bf16(v.z,h2,l2); split_bf16(v.w,h3,l3);
                uint2 hp, lp;
                hp.x = h0 | (h1<<16); hp.y = h2 | (h3<<16);
                lp.x = l0 | (l1<<16); lp.y = l2 | (l3<<16);
                char* p = dst + swz(m, kq * 2);
                *(uint2*)p = hp;
                *(uint2*)(p + 8192) = lp;
            }
        }
        if (w >= 2) {
            const char* src = Bbase + (size_t)kt * b_kt + ((w - 2) << 13) + l * 16;
            char* d = dst + 16384 + ((w - 2) << 13);
            #pragma unroll
            for (int i = 0; i < 8; ++i)
                gll16(src + i * 1024, d + i * 1024);
        }
    };

    stage(0, 0);
    int cur = 0;
    for (int kt = 0; kt < KT; ++kt) {
        __syncthreads();                       // stage(cur) complete (vm+lgkm drain)
        if (kt + 1 < KT) stage(cur ^ 1, kt + 1);
        const char* As = smem + (cur << 15);
        const char* Bs = As + 16384;
        #pragma unroll
        for (int ks = 0; ks < 2; ++ks) {
            bf16x8 afr[2][2], bfr[2][2];
            #pragma unroll
            for (int mf = 0; mf < 2; ++mf) {
                int off = swz(wr * 32 + mf * 16 + l15, ks * 64 + lg * 16);
                afr[mf][0] = *(const bf16x8*)(As + off);
                afr[mf][1] = *(const bf16x8*)(As + 8192 + off);
            }
            #pragma unroll
            for (int nf = 0; nf < 2; ++nf) {
                int off = swz(wc * 32 + nf * 16 + l15, ks * 64 + lg * 16);
                bfr[nf][0] = *(const bf16x8*)(Bs + off);
                bfr[nf][1] = *(const bf16x8*)(Bs + 8192 + off);
            }
            #pragma unroll
            for (int mf = 0; mf < 2; ++mf)
                #pragma unroll
                for (int nf = 0; nf < 2; ++nf) {
                    acc[mf][nf] = __builtin_amdgcn_mfma_f32_16x16x32_bf16(
                        afr[mf][0], bfr[nf][0], acc[mf][nf], 0, 0, 0);
                    acc[mf][nf] = __builtin_amdgcn_mfma_f32_16x16x32_bf16(
                        afr[mf][1], bfr[nf][0], acc[mf][nf], 0, 0, 0);
                    acc[mf][nf] = __builtin_amdgcn_mfma_f32_16x16x32_bf16(
                        afr[mf][0], bfr[nf][1], acc[mf][nf], 0, 0, 0);
                }
        }
        cur ^= 1;
    }

    if (emode == 0) {
        float* C = Cf + (size_t)(mt * 64) * ldc + nt * 64;
        #pragma unroll
        for (int nf = 0; nf < 2; ++nf) {
            int n = wc * 32 + nf * 16 + l15;
            float bv = bias ? bias[nt * 64 + n] : 0.f;
            #pragma unroll
            for (int mf = 0; mf < 2; ++mf)
                #pragma unroll
                for (int r = 0; r < 4; ++r) {
                    int row = wr * 32 + mf * 16 + lg * 4 + r;
                    C[(size_t)row * ldc + n] = acc[mf][nf][r] + bv;
                }
        }
    } else {
        __syncthreads();
        float* sm = (float*)smem;                       // [64][72] fp32 bounce
        #pragma unroll
        for (int nf = 0; nf < 2; ++nf) {
            int n = wc * 32 + nf * 16 + l15;
            float bv = bias ? bias[nt * 64 + n] : 0.f;
            #pragma unroll
            for (int mf = 0; mf < 2; ++mf)
                #pragma unroll
                for (int r = 0; r < 4; ++r) {
                    float v = acc[mf][nf][r] + bv;
                    if (emode == 2) v = fmaxf(v, 0.f);
                    sm[(wr * 32 + mf * 16 + lg * 4 + r) * 72 + n] = v;
                }
        }
        __syncthreads();
        char* dst = Csp + (size_t)mt * c_mt + (size_t)nt * c_nt
                        + (size_t)c_s1 * z1 + (size_t)c_s2 * z2;
        #pragma unroll
        for (int rep = 0; rep < 2; ++rep) {
            int r0 = (tid >> 3) + rep * 32;   // tile row (m for A-style, n for trans)
            int c8 = (tid & 7) * 8;           // 8-wide col chunk
            float v[8];
            if (emode == 3) {
                #pragma unroll
                for (int i = 0; i < 8; ++i) v[i] = sm[(c8 + i) * 72 + r0];
            } else {
                #pragma unroll
                for (int i = 0; i < 8; ++i) v[i] = sm[r0 * 72 + c8 + i];
            }
            unsigned h[8], lo[8];
            #pragma unroll
            for (int i = 0; i < 8; ++i) split_bf16(v[i], h[i], lo[i]);
            uint4 hp, lp;
            hp.x = h[0] | (h[1]<<16); hp.y = h[2] | (h[3]<<16);
            hp.z = h[4] | (h[5]<<16); hp.w = h[6] | (h[7]<<16);
            lp.x = lo[0] | (lo[1]<<16); lp.y = lo[2] | (lo[3]<<16);
            lp.z = lo[4] | (lo[5]<<16); lp.w = lo[6] | (lo[7]<<16);
            char* p = dst + swz(r0, c8 * 2);
            *(uint4*)p = hp;
            *(uint4*)(p + 8192) = lp;
        }
    }
}

// ---------------------------------------------------------------------------
// Fused attention scores + mask + softmax (unchanged fp32 path).
// ---------------------------------------------------------------------------
__global__ __launch_bounds__(256) void attn_softmax_kernel(
    const float* __restrict__ Q, const float* __restrict__ K,
    const int* __restrict__ seq, float* __restrict__ P, int causal)
{
    int hb = blockIdx.y;
    int h  = hb >> 3;
    int b  = hb & 7;
    int q0 = blockIdx.x * 16;

    __shared__ float Qs[16][DHEAD + 1];
    __shared__ float Ks[16][DHEAD + 1];

    int tid = threadIdx.x;
    int tx = tid & 15, ty = tid >> 4;

    {
        int r  = tid >> 4;
        int e4 = (tid & 15) * 4;
        float4 qv = *(const float4*)(Q + ((size_t)(b * SEQ + q0 + r)) * D_MODEL + h * DHEAD + e4);
        Qs[r][e4 + 0] = qv.x; Qs[r][e4 + 1] = qv.y;
        Qs[r][e4 + 2] = qv.z; Qs[r][e4 + 3] = qv.w;
    }

    const float scale = 0.044194173824159216f;
    float logit[32];
    int q = q0 + ty;

    for (int c = 0; c < 32; ++c) {
        int s0 = c * 16;
        __syncthreads();
        {
            int r  = tid >> 4;
            int e4 = (tid & 15) * 4;
            float4 kv = *(const float4*)(K + ((size_t)(b * SEQ + s0 + r)) * D_MODEL + h * DHEAD + e4);
            Ks[r][e4 + 0] = kv.x; Ks[r][e4 + 1] = kv.y;
            Ks[r][e4 + 2] = kv.z; Ks[r][e4 + 3] = kv.w;
        }
        __syncthreads();
        float dot = 0.f;
        #pragma unroll
        for (int e = 0; e < DHEAD; ++e) dot += Qs[ty][e] * Ks[tx][e];
        int s = s0 + tx;
        bool masked = (seq[b * SEQ + s] == 0);
        if (causal) masked = masked || (s > q);
        logit[c] = masked ? -INFINITY : dot * scale;
    }

    float mx = -INFINITY;
    #pragma unroll
    for (int c = 0; c < 32; ++c) mx = fmaxf(mx, logit[c]);
    #pragma unroll
    for (int m = 1; m < 16; m <<= 1) mx = fmaxf(mx, __shfl_xor(mx, m, 64));
    float sum = 0.f;
    #pragma unroll
    for (int c = 0; c < 32; ++c) {
        float e = __expf(logit[c] - mx);
        logit[c] = e;
        sum += e;
    }
    #pragma unroll
    for (int m = 1; m < 16; m <<= 1) sum += __shfl_xor(sum, m, 64);
    float inv = 1.0f / sum;

    float* prow = P + ((size_t)(hb * SEQ + q)) * SEQ;
    #pragma unroll
    for (int c = 0; c < 32; ++c) prow[c * 16 + tx] = logit[c] * inv;
}

// ---------------------------------------------------------------------------
// Residual-add + LayerNorm; also emits the split tiles of the output.
// ---------------------------------------------------------------------------
__global__ __launch_bounds__(256) void add_ln_kernel(
    const float* __restrict__ a, const float* __restrict__ res,
    const float* __restrict__ g, const float* __restrict__ bta,
    float* __restrict__ outp, char* __restrict__ split)
{
    int wave = threadIdx.x >> 6;
    int lane = threadIdx.x & 63;
    int row  = (blockIdx.x << 2) + wave;
    const float* ap = a   + (size_t)row * D_MODEL + lane * 8;
    const float* rp = res + (size_t)row * D_MODEL + lane * 8;
    float4 a0 = *(const float4*)ap;
    float4 a1 = *(const float4*)(ap + 4);
    float4 r0 = *(const float4*)rp;
    float4 r1 = *(const float4*)(rp + 4);
    float v[8];
    v[0] = a0.x + r0.x; v[1] = a0.y + r0.y; v[2] = a0.z + r0.z; v[3] = a0.w + r0.w;
    v[4] = a1.x + r1.x; v[5] = a1.y + r1.y; v[6] = a1.z + r1.z; v[7] = a1.w + r1.w;
    float s = 0.f;
    #pragma unroll
    for (int i = 0; i < 8; ++i) s += v[i];
    #pragma unroll
    for (int m = 1; m < 64; m <<= 1) s += __shfl_xor(s, m, 64);
    float mu = s * (1.0f / 512.0f);
    float vs = 0.f;
    #pragma unroll
    for (int i = 0; i < 8; ++i) { float d = v[i] - mu; vs += d * d; }
    #pragma unroll
    for (int m = 1; m < 64; m <<= 1) vs += __shfl_xor(vs, m, 64);
    float inv = rsqrtf(vs * (1.0f / 512.0f) + 1e-5f);
    int col = lane * 8;
    float o[8];
    #pragma unroll
    for (int i = 0; i < 8; ++i)
        o[i] = (v[i] - mu) * inv * g[col + i] + bta[col + i];
    float4* op = (float4*)(outp + (size_t)row * D_MODEL + col);
    op[0] = make_float4(o[0], o[1], o[2], o[3]);
    op[1] = make_float4(o[4], o[5], o[6], o[7]);

    unsigned h[8], lo[8];
    #pragma unroll
    for (int i = 0; i < 8; ++i) split_bf16(o[i], h[i], lo[i]);
    uint4 hp, lp;
    hp.x = h[0] | (h[1]<<16); hp.y = h[2] | (h[3]<<16);
    hp.z = h[4] | (h[5]<<16); hp.w = h[6] | (h[7]<<16);
    lp.x = lo[0] | (lo[1]<<16); lp.y = lo[2] | (lo[3]<<16);
    lp.z = lo[4] | (lo[5]<<16); lp.w = lo[6] | (lo[7]<<16);
    int mt = row >> 6, m = row & 63;
    int kt = col >> 6, kl = col & 63;
    char* tp = split + (size_t)(mt * 8 + kt) * TB + swz(m, kl * 2);
    *(uint4*)tp = hp;
    *(uint4*)(tp + 8192) = lp;
}

// ---------------------------------------------------------------------------
__global__ __launch_bounds__(256) void copy_kernel(
    const float4* __restrict__ src, float4* __restrict__ dst, int n4)
{
    int i = blockIdx.x * blockDim.x + threadIdx.x;
    if (i < n4) dst[i] = src[i];
}

// ---------------------------------------------------------------------------
extern "C" void kernel_launch(void* const* d_in, const int* in_sizes, int n_in,
                              void* d_out, int out_size, void* d_ws, size_t ws_size,
                              hipStream_t stream)
{
    (void)in_sizes; (void)n_in; (void)out_size; (void)ws_size;

    const int*   tgt_seq    = (const int*)d_in[0];
    const int*   tgt_pos    = (const int*)d_in[1];
    const int*   src_seq    = (const int*)d_in[2];
    const float* enc_output = (const float*)d_in[3];
    const float* tgt_emb    = (const float*)d_in[4];
    const float* pos_emb    = (const float*)d_in[5];
    const float* slf_wq = (const float*)d_in[6];
    const float* slf_wk = (const float*)d_in[7];
    const float* slf_wv = (const float*)d_in[8];
    const float* slf_pw = (const float*)d_in[9];
    const float* slf_pb = (const float*)d_in[10];
    const float* slf_g  = (const float*)d_in[11];
    const float* slf_b  = (const float*)d_in[12];
    const float* enc_wq = (const float*)d_in[13];
    const float* enc_wk = (const float*)d_in[14];
    const float* enc_wv = (const float*)d_in[15];
    const float* enc_pw = (const float*)d_in[16];
    const float* enc_pb = (const float*)d_in[17];
    const float* enc_g  = (const float*)d_in[18];
    const float* enc_b  = (const float*)d_in[19];
    const float* ffn_w1 = (const float*)d_in[20];
    const float* ffn_b1 = (const float*)d_in[21];
    const float* ffn_w2 = (const float*)d_in[22];
    const float* ffn_b2 = (const float*)d_in[23];
    const float* ffn_g  = (const float*)d_in[24];
    const float* ffn_b  = (const float*)d_in[25];

    float* out = (float*)d_out;

    // workspace layout (bytes):
    //   x 8M | xsplit 8M | qb 8M | kb 8M | vsplit 8M | obsplit 8M |
    //   encsplit 8M | hbsplit 32M | wbuf 16M          = 104 MB total
    char* wsb = (char*)d_ws;
    float* x        = (float*)(wsb);
    char*  xsplit   = wsb + (8u  << 20);
    float* qb       = (float*)(wsb + (16u << 20));
    float* kb       = (float*)(wsb + (24u << 20));
    char*  vsplit   = wsb + (32u << 20);
    char*  obsplit  = wsb + (40u << 20);
    char*  encsplit = wsb + (48u << 20);
    char*  hbsplit  = wsb + (56u << 20);
    char*  wbuf     = wsb + (88u << 20);
    float* tmp = qb;   // proj/ffn2 output aliases qb (dead after softmax)

    float* slf_attn_out = out + (size_t)ROWS * D_MODEL;
    float* enc_attn_out = slf_attn_out + (size_t)NLAYER * NHEAD * BATCH * SEQ * SEQ;

    const size_t W_STRIDE    = (size_t)NHEAD * D_MODEL * DHEAD;      // 262144
    const size_t PW_STRIDE   = (size_t)D_MODEL * D_MODEL;            // 262144
    const size_t ATTN_STRIDE = (size_t)NHEAD * BATCH * SEQ * SEQ;
    const long T = TB;

    embed_kernel<<<ROWS, 128, 0, stream>>>(tgt_seq, tgt_pos, tgt_emb, pos_emb, x, xsplit);
    asplit_kernel<<<512, 256, 0, stream>>>(enc_output, encsplit);

    for (int l = 0; l < NLAYER; ++l) {
        wsplit_kernel<<<1024, 256, 0, stream>>>(
            slf_wq + l * W_STRIDE, slf_wk + l * W_STRIDE, slf_wv + l * W_STRIDE,
            slf_pw + l * PW_STRIDE,
            enc_wq + l * W_STRIDE, enc_wk + l * W_STRIDE, enc_wv + l * W_STRIDE,
            enc_pw + l * PW_STRIDE,
            ffn_w1 + (size_t)l * D_MODEL * DFFN, ffn_w2 + (size_t)l * DFFN * D_MODEL,
            wbuf);
        const char* Wq  = wbuf;
        const char* Wk  = wbuf + 64 * T;
        const char* Wv  = wbuf + 128 * T;
        const char* Pw  = wbuf + 192 * T;
        const char* eWq = wbuf + 256 * T;
        const char* eWk = wbuf + 320 * T;
        const char* eWv = wbuf + 384 * T;
        const char* ePw = wbuf + 448 * T;
        const char* W1  = wbuf + 512 * T;
        const char* W2  = wbuf + 768 * T;

        // ===================== self-attention =====================
        gemm2_kernel<<<dim3(8, 64, 1), 256, 0, stream>>>(
            xsplit, nullptr, Wq, qb, nullptr, nullptr, 8,
            8*T, 0, 0, 0,   8*T, T, 0, 0,   512, 0, 0, 0, 0, 1, 0, 0);
        gemm2_kernel<<<dim3(8, 64, 1), 256, 0, stream>>>(
            xsplit, nullptr, Wk, kb, nullptr, nullptr, 8,
            8*T, 0, 0, 0,   8*T, T, 0, 0,   512, 0, 0, 0, 0, 1, 0, 0);
        gemm2_kernel<<<dim3(8, 64, 1), 256, 0, stream>>>(
            xsplit, nullptr, Wv, nullptr, vsplit, nullptr, 8,
            8*T, 0, 0, 0,   8*T, T, 0, 0,   0, 8*T, T, 0, 0, 1, 0, 3);
        float* P = slf_attn_out + (size_t)l * ATTN_STRIDE;
        attn_softmax_kernel<<<dim3(SEQ / 16, NHEAD * BATCH), 256, 0, stream>>>(
            qb, kb, tgt_seq, P, 1);
        gemm2_kernel<<<dim3(1, 8, 64), 256, 0, stream>>>(
            nullptr, P, vsplit, nullptr, obsplit, nullptr, 8,
            0, 512, (long)BATCH * SEQ * SEQ, (long)SEQ * SEQ,
            0, 8*T, T, 64*T,
            0, 8*T, 0, T, 64*T, BATCH, 1, 1);
        gemm2_kernel<<<dim3(8, 64, 1), 256, 0, stream>>>(
            obsplit, nullptr, Pw, tmp, nullptr, slf_pb + l * D_MODEL, 8,
            8*T, 0, 0, 0,   8*T, T, 0, 0,   512, 0, 0, 0, 0, 1, 0, 0);
        add_ln_kernel<<<ROWS / 4, 256, 0, stream>>>(tmp, x, slf_g + l * D_MODEL,
                                                    slf_b + l * D_MODEL, x, xsplit);

        // ===================== cross-attention =====================
        gemm2_kernel<<<dim3(8, 64, 1), 256, 0, stream>>>(
            xsplit, nullptr, eWq, qb, nullptr, nullptr, 8,
            8*T, 0, 0, 0,   8*T, T, 0, 0,   512, 0, 0, 0, 0, 1, 0, 0);
        gemm2_kernel<<<dim3(8, 64, 1), 256, 0, stream>>>(
            encsplit, nullptr, eWk, kb, nullptr, nullptr, 8,
            8*T, 0, 0, 0,   8*T, T, 0, 0,   512, 0, 0, 0, 0, 1, 0, 0);
        gemm2_kernel<<<dim3(8, 64, 1), 256, 0, stream>>>(
            encsplit, nullptr, eWv, nullptr, vsplit, nullptr, 8,
            8*T, 0, 0, 0,   8*T, T, 0, 0,   0, 8*T, T, 0, 0, 1, 0, 3);
        P = enc_attn_out + (size_t)l * ATTN_STRIDE;
        attn_softmax_kernel<<<dim3(SEQ / 16, NHEAD * BATCH), 256, 0, stream>>>(
            qb, kb, src_seq, P, 0);
        gemm2_kernel<<<dim3(1, 8, 64), 256, 0, stream>>>(
            nullptr, P, vsplit, nullptr, obsplit, nullptr, 8,
            0, 512, (long)BATCH * SEQ * SEQ, (long)SEQ * SEQ,
            0, 8*T, T, 64*T,
            0, 8*T, 0, T, 64*T, BATCH, 1, 1);
        gemm2_kernel<<<dim3(8, 64, 1), 256, 0, stream>>>(
            obsplit, nullptr, ePw, tmp, nullptr, enc_pb + l * D_MODEL, 8,
            8*T, 0, 0, 0,   8*T, T, 0, 0,   512, 0, 0, 0, 0, 1, 0, 0);
        add_ln_kernel<<<ROWS / 4, 256, 0, stream>>>(tmp, x, enc_g + l * D_MODEL,
                                                    enc_b + l * D_MODEL, x, xsplit);

        // ===================== FFN =====================
        gemm2_kernel<<<dim3(32, 64, 1), 256, 0, stream>>>(
            xsplit, nullptr, W1, nullptr, hbsplit, ffn_b1 + l * DFFN, 8,
            8*T, 0, 0, 0,   8*T, T, 0, 0,   0, 32*T, T, 0, 0, 1, 0, 2);
        gemm2_kernel<<<dim3(8, 64, 1), 256, 0, stream>>>(
            hbsplit, nullptr, W2, tmp, nullptr, ffn_b2 + l * D_MODEL, 32,
            32*T, 0, 0, 0,   32*T, T, 0, 0,   512, 0, 0, 0, 0, 1, 0, 0);
        add_ln_kernel<<<ROWS / 4, 256, 0, stream>>>(tmp, x, ffn_g + l * D_MODEL,
                                                    ffn_b + l * D_MODEL, x, xsplit);
    }

    int n4 = ROWS * D_MODEL / 4;
    copy_kernel<<<(n4 + 255) / 256, 256, 0, stream>>>((const float4*)x, (float4*)out, n4);
}